// Round 1
// baseline (806.939 us; speedup 1.0000x reference)
//
#include <hip/hip_runtime.h>
#include <math.h>

#define NN 100000
#define NE 3200000

// ---------------- degree / dinv ----------------
__global__ void deg_init_kernel(float* deg, int n) {
    int i = blockIdx.x * blockDim.x + threadIdx.x;
    if (i < n) deg[i] = 1.0f;   // self-loop contribution
}

__global__ void deg_count_kernel(const int* __restrict__ dst, float* deg, int e) {
    int i = blockIdx.x * blockDim.x + threadIdx.x;
    if (i < e) atomicAdd(&deg[dst[i]], 1.0f);
}

__global__ void dinv_kernel(float* deg, int n) {
    int i = blockIdx.x * blockDim.x + threadIdx.x;
    if (i < n) deg[i] = rsqrtf(deg[i]);   // deg >= 1 always
}

// ---------------- layer 1 GEMM: h1 = x @ W1^T, agg1 = h1*dinv^2 + b1 ----------------
// block = 256 threads = 8 rows x 32 cols
__global__ void gemm1_kernel(const float* __restrict__ x, const float* __restrict__ W1,
                             const float* __restrict__ b1, const float* __restrict__ dinv,
                             float* __restrict__ h1, float* __restrict__ agg1, int n) {
    __shared__ float sWt[64 * 32];   // sWt[k*32 + c] = W1[c*64 + k]  (transposed, conflict-free)
    __shared__ float sX[8 * 64];
    int tid = threadIdx.x;
    for (int idx = tid; idx < 64 * 32; idx += 256) {
        int k = idx >> 5, c = idx & 31;
        sWt[idx] = W1[c * 64 + k];
    }
    int row0 = blockIdx.x * 8;
    for (int idx = tid; idx < 8 * 64; idx += 256) {
        int r = row0 + (idx >> 6);
        sX[idx] = (r < n) ? x[r * 64 + (idx & 63)] : 0.0f;
    }
    __syncthreads();
    int lr = tid >> 5;      // 0..7
    int c  = tid & 31;      // 0..31
    int r = row0 + lr;
    if (r < n) {
        float acc = 0.0f;
#pragma unroll
        for (int k = 0; k < 64; ++k) acc += sX[lr * 64 + k] * sWt[k * 32 + c];
        h1[r * 32 + c] = acc;
        float di = dinv[r];
        agg1[r * 32 + c] = acc * di * di + b1[c];
    }
}

// ---------------- scatter 1: agg1[dst] += h1[src] * norm ----------------
// thread t -> edge t>>5, col t&31
__global__ void scatter1_kernel(const int* __restrict__ src, const int* __restrict__ dst,
                                const float* __restrict__ dinv, const float* __restrict__ h1,
                                float* __restrict__ agg1, int e) {
    int t = blockIdx.x * blockDim.x + threadIdx.x;
    int ei = t >> 5;
    if (ei < e) {
        int c = t & 31;
        int s = src[ei], d = dst[ei];
        float norm = dinv[s] * dinv[d];
        atomicAdd(&agg1[d * 32 + c], h1[s * 32 + c] * norm);
    }
}

// ---------------- layer 2 GEMM: h2 = relu(agg1) @ W2^T, z = h2*dinv^2 + b2 ----------------
// block = 256 threads = 16 rows x 16 cols
__global__ void gemm2_kernel(const float* __restrict__ agg1, const float* __restrict__ W2,
                             const float* __restrict__ b2, const float* __restrict__ dinv,
                             float* __restrict__ h2, float* __restrict__ z, int n) {
    __shared__ float sWt[32 * 16];   // sWt[k*16 + c] = W2[c*32 + k]
    __shared__ float sH[16 * 32];
    int tid = threadIdx.x;
    for (int idx = tid; idx < 32 * 16; idx += 256) {
        int k = idx >> 4, c = idx & 15;
        sWt[idx] = W2[c * 32 + k];
    }
    int row0 = blockIdx.x * 16;
    for (int idx = tid; idx < 16 * 32; idx += 256) {
        int r = row0 + (idx >> 5);
        float v = (r < n) ? agg1[r * 32 + (idx & 31)] : 0.0f;
        sH[idx] = fmaxf(v, 0.0f);     // fused ReLU
    }
    __syncthreads();
    int lr = tid >> 4;    // 0..15
    int c  = tid & 15;    // 0..15
    int r = row0 + lr;
    if (r < n) {
        float acc = 0.0f;
#pragma unroll
        for (int k = 0; k < 32; ++k) acc += sH[lr * 32 + k] * sWt[k * 16 + c];
        h2[r * 16 + c] = acc;
        float di = dinv[r];
        z[r * 16 + c] = acc * di * di + b2[c];
    }
}

// ---------------- scatter 2: z[dst] += h2[src] * norm ----------------
__global__ void scatter2_kernel(const int* __restrict__ src, const int* __restrict__ dst,
                                const float* __restrict__ dinv, const float* __restrict__ h2,
                                float* __restrict__ z, int e) {
    int t = blockIdx.x * blockDim.x + threadIdx.x;
    int ei = t >> 4;
    if (ei < e) {
        int c = t & 15;
        int s = src[ei], d = dst[ei];
        float norm = dinv[s] * dinv[d];
        atomicAdd(&z[d * 16 + c], h2[s * 16 + c] * norm);
    }
}

// ---------------- decode: out[e] = sigmoid(dot(z[src], z[dst])) ----------------
__global__ void decode_kernel(const int* __restrict__ src, const int* __restrict__ dst,
                              const float* __restrict__ z, float* __restrict__ out, int e) {
    int i = blockIdx.x * blockDim.x + threadIdx.x;
    if (i < e) {
        int s = src[i], d = dst[i];
        const float4* zs = (const float4*)(z + (size_t)s * 16);
        const float4* zd = (const float4*)(z + (size_t)d * 16);
        float acc = 0.0f;
#pragma unroll
        for (int q = 0; q < 4; ++q) {
            float4 a = zs[q], b = zd[q];
            acc += a.x * b.x + a.y * b.y + a.z * b.z + a.w * b.w;
        }
        out[i] = 1.0f / (1.0f + expf(-acc));
    }
}

extern "C" void kernel_launch(void* const* d_in, const int* in_sizes, int n_in,
                              void* d_out, int out_size, void* d_ws, size_t ws_size,
                              hipStream_t stream) {
    const float* x   = (const float*)d_in[0];
    const int* eidx  = (const int*)d_in[1];     // [2, NE] flattened
    const float* W1  = (const float*)d_in[2];
    const float* b1  = (const float*)d_in[3];
    const float* W2  = (const float*)d_in[4];
    const float* b2  = (const float*)d_in[5];
    float* out = (float*)d_out;

    const int n = NN;
    const int e = NE;
    const int* src = eidx;
    const int* dst = eidx + e;

    // workspace layout (floats)
    float* ws   = (float*)d_ws;
    float* dinv = ws;                 // N   (used first as deg)
    float* h1   = ws + n;             // N*32
    float* agg1 = h1 + (size_t)n*32;  // N*32
    float* h2   = agg1 + (size_t)n*32;// N*16
    float* z    = h2 + (size_t)n*16;  // N*16

    dim3 blk(256);

    // degree -> dinv
    deg_init_kernel<<<(n + 255) / 256, blk, 0, stream>>>(dinv, n);
    deg_count_kernel<<<(e + 255) / 256, blk, 0, stream>>>(dst, dinv, e);
    dinv_kernel<<<(n + 255) / 256, blk, 0, stream>>>(dinv, n);

    // layer 1
    gemm1_kernel<<<(n + 7) / 8, blk, 0, stream>>>(x, W1, b1, dinv, h1, agg1, n);
    {
        long long tot = (long long)e * 32;
        scatter1_kernel<<<(unsigned)((tot + 255) / 256), blk, 0, stream>>>(src, dst, dinv, h1, agg1, e);
    }

    // layer 2
    gemm2_kernel<<<(n + 15) / 16, blk, 0, stream>>>(agg1, W2, b2, dinv, h2, z, n);
    {
        long long tot = (long long)e * 16;
        scatter2_kernel<<<(unsigned)((tot + 255) / 256), blk, 0, stream>>>(src, dst, dinv, h2, z, e);
    }

    // decode
    decode_kernel<<<(e + 255) / 256, blk, 0, stream>>>(src, dst, z, out, e);
}

// Round 2
// 805.590 us; speedup vs baseline: 1.0017x; 1.0017x over previous
//
#include <hip/hip_runtime.h>
#include <math.h>

#define NN 100000
#define NE 3200000
#define NB1 ((NN + 255) / 256)   // 391 scan blocks

// ---------------- histogram: counts[d]++ ----------------
__global__ void hist_kernel(const int* __restrict__ dst, int* __restrict__ counts, int e) {
    int i = blockIdx.x * blockDim.x + threadIdx.x;
    if (i < e) atomicAdd(&counts[dst[i]], 1);
}

// ---------------- exclusive scan (3 phases) ----------------
__global__ void scan_blocks_kernel(const int* __restrict__ counts, int* __restrict__ offs,
                                   int* __restrict__ bsums, int n) {
    __shared__ int s[256];
    int tid = threadIdx.x;
    int i = blockIdx.x * 256 + tid;
    int v = (i < n) ? counts[i] : 0;
    s[tid] = v;
    __syncthreads();
    for (int off = 1; off < 256; off <<= 1) {
        int t = (tid >= off) ? s[tid - off] : 0;
        __syncthreads();
        s[tid] += t;
        __syncthreads();
    }
    if (i < n) offs[i] = s[tid] - v;          // block-local exclusive
    if (tid == 255) bsums[blockIdx.x] = s[255];
}

__global__ void scan_tops_kernel(int* __restrict__ bsums, int nb) {
    __shared__ int s[512];
    int tid = threadIdx.x;
    int v = (tid < nb) ? bsums[tid] : 0;
    s[tid] = v;
    __syncthreads();
    for (int off = 1; off < 512; off <<= 1) {
        int t = (tid >= off) ? s[tid - off] : 0;
        __syncthreads();
        s[tid] += t;
        __syncthreads();
    }
    if (tid < nb) bsums[tid] = s[tid] - v;    // exclusive
}

__global__ void scan_add_kernel(int* __restrict__ offs, const int* __restrict__ bsums,
                                int* __restrict__ cursor, int n) {
    int i = blockIdx.x * blockDim.x + threadIdx.x;
    if (i < n) {
        int o = offs[i] + bsums[i >> 8];
        offs[i] = o;
        cursor[i] = o;
    }
}

// ---------------- dinv = rsqrt(indeg + 1) ----------------
__global__ void dinv_kernel(const int* __restrict__ counts, float* __restrict__ dinv, int n) {
    int i = blockIdx.x * blockDim.x + threadIdx.x;
    if (i < n) dinv[i] = rsqrtf((float)counts[i] + 1.0f);
}

// ---------------- CSR fill: adj[pos] = src ----------------
__global__ void fill_kernel(const int* __restrict__ src, const int* __restrict__ dst,
                            int* __restrict__ cursor, int* __restrict__ adj, int e) {
    int i = blockIdx.x * blockDim.x + threadIdx.x;
    if (i < e) {
        int d = dst[i];
        int p = atomicAdd(&cursor[d], 1);
        adj[p] = src[i];
    }
}

// ---------------- layer 1 GEMM: g1 = (x @ W1^T) * dinv[row] ----------------
// block = 256 threads = 8 rows x 32 cols
__global__ void gemm1_kernel(const float* __restrict__ x, const float* __restrict__ W1,
                             const float* __restrict__ dinv, float* __restrict__ g1, int n) {
    __shared__ float sWt[64 * 32];   // sWt[k*32 + c] = W1[c*64 + k]
    __shared__ float sX[8 * 64];
    int tid = threadIdx.x;
    for (int idx = tid; idx < 64 * 32; idx += 256) {
        int k = idx >> 5, c = idx & 31;
        sWt[idx] = W1[c * 64 + k];
    }
    int row0 = blockIdx.x * 8;
    for (int idx = tid; idx < 8 * 64; idx += 256) {
        int r = row0 + (idx >> 6);
        sX[idx] = (r < n) ? x[r * 64 + (idx & 63)] : 0.0f;
    }
    __syncthreads();
    int lr = tid >> 5;      // 0..7
    int c  = tid & 31;      // 0..31
    int r = row0 + lr;
    if (r < n) {
        float acc = 0.0f;
#pragma unroll
        for (int k = 0; k < 64; ++k) acc += sX[lr * 64 + k] * sWt[k * 32 + c];
        g1[r * 32 + c] = acc * dinv[r];
    }
}

// ---------------- layer 1 aggregation (gather): agg1[d] = b1 + dinv[d]*(g1[d] + sum g1[s]) ----------------
// thread t: node = t>>5, col = t&31
__global__ void agg1_kernel(const int* __restrict__ offs, const int* __restrict__ counts,
                            const int* __restrict__ adj, const float* __restrict__ dinv,
                            const float* __restrict__ g1, const float* __restrict__ b1,
                            float* __restrict__ agg1, int n) {
    int t = blockIdx.x * blockDim.x + threadIdx.x;
    int node = t >> 5;
    if (node >= n) return;
    int c = t & 31;
    int beg = offs[node];
    int deg = counts[node];
    float acc = g1[node * 32 + c];             // self-loop term (pre-scaled by dinv)
    for (int j = 0; j < deg; ++j) {
        int s = adj[beg + j];
        acc += g1[s * 32 + c];
    }
    agg1[node * 32 + c] = b1[c] + dinv[node] * acc;
}

// ---------------- layer 2 GEMM: g2 = (relu(agg1) @ W2^T) * dinv[row] ----------------
// block = 256 threads = 16 rows x 16 cols
__global__ void gemm2_kernel(const float* __restrict__ agg1, const float* __restrict__ W2,
                             const float* __restrict__ dinv, float* __restrict__ g2, int n) {
    __shared__ float sWt[32 * 16];   // sWt[k*16 + c] = W2[c*32 + k]
    __shared__ float sH[16 * 32];
    int tid = threadIdx.x;
    for (int idx = tid; idx < 32 * 16; idx += 256) {
        int k = idx >> 4, c = idx & 15;
        sWt[idx] = W2[c * 32 + k];
    }
    int row0 = blockIdx.x * 16;
    for (int idx = tid; idx < 16 * 32; idx += 256) {
        int r = row0 + (idx >> 5);
        float v = (r < n) ? agg1[r * 32 + (idx & 31)] : 0.0f;
        sH[idx] = fmaxf(v, 0.0f);     // fused ReLU
    }
    __syncthreads();
    int lr = tid >> 4;    // 0..15
    int c  = tid & 15;    // 0..15
    int r = row0 + lr;
    if (r < n) {
        float acc = 0.0f;
#pragma unroll
        for (int k = 0; k < 32; ++k) acc += sH[lr * 32 + k] * sWt[k * 16 + c];
        g2[r * 16 + c] = acc * dinv[r];
    }
}

// ---------------- layer 2 aggregation: z[d] = b2 + dinv[d]*(g2[d] + sum g2[s]) ----------------
// thread t: node = t>>4, col = t&15
__global__ void agg2_kernel(const int* __restrict__ offs, const int* __restrict__ counts,
                            const int* __restrict__ adj, const float* __restrict__ dinv,
                            const float* __restrict__ g2, const float* __restrict__ b2,
                            float* __restrict__ z, int n) {
    int t = blockIdx.x * blockDim.x + threadIdx.x;
    int node = t >> 4;
    if (node >= n) return;
    int c = t & 15;
    int beg = offs[node];
    int deg = counts[node];
    float acc = g2[node * 16 + c];
    for (int j = 0; j < deg; ++j) {
        int s = adj[beg + j];
        acc += g2[s * 16 + c];
    }
    z[node * 16 + c] = b2[c] + dinv[node] * acc;
}

// ---------------- decode: out[e] = sigmoid(dot(z[src], z[dst])) ----------------
__global__ void decode_kernel(const int* __restrict__ src, const int* __restrict__ dst,
                              const float* __restrict__ z, float* __restrict__ out, int e) {
    int i = blockIdx.x * blockDim.x + threadIdx.x;
    if (i < e) {
        int s = src[i], d = dst[i];
        const float4* zs = (const float4*)(z + (size_t)s * 16);
        const float4* zd = (const float4*)(z + (size_t)d * 16);
        float acc = 0.0f;
#pragma unroll
        for (int q = 0; q < 4; ++q) {
            float4 a = zs[q], b = zd[q];
            acc += a.x * b.x + a.y * b.y + a.z * b.z + a.w * b.w;
        }
        out[i] = 1.0f / (1.0f + expf(-acc));
    }
}

extern "C" void kernel_launch(void* const* d_in, const int* in_sizes, int n_in,
                              void* d_out, int out_size, void* d_ws, size_t ws_size,
                              hipStream_t stream) {
    const float* x   = (const float*)d_in[0];
    const int* eidx  = (const int*)d_in[1];     // [2, NE] flattened
    const float* W1  = (const float*)d_in[2];
    const float* b1  = (const float*)d_in[3];
    const float* W2  = (const float*)d_in[4];
    const float* b2  = (const float*)d_in[5];
    float* out = (float*)d_out;

    const int n = NN;
    const int e = NE;
    const int* src = eidx;
    const int* dst = eidx + e;

    // workspace layout
    int* counts  = (int*)d_ws;                 // N
    int* offs    = counts + n;                 // N
    int* cursor  = offs + n;                   // N
    int* bsums   = cursor + n;                 // 512
    int* adj     = bsums + 512;                // E
    float* dinv  = (float*)(adj + e);          // N
    float* g1    = dinv + n;                   // N*32
    float* agg1  = g1 + (size_t)n * 32;        // N*32
    float* g2    = agg1 + (size_t)n * 32;      // N*16
    float* z     = g2 + (size_t)n * 16;        // N*16

    dim3 blk(256);

    // CSR build
    hipMemsetAsync(counts, 0, (size_t)n * sizeof(int), stream);
    hist_kernel<<<(e + 255) / 256, blk, 0, stream>>>(dst, counts, e);
    scan_blocks_kernel<<<NB1, blk, 0, stream>>>(counts, offs, bsums, n);
    scan_tops_kernel<<<1, 512, 0, stream>>>(bsums, NB1);
    scan_add_kernel<<<NB1, blk, 0, stream>>>(offs, bsums, cursor, n);
    dinv_kernel<<<NB1, blk, 0, stream>>>(counts, dinv, n);
    fill_kernel<<<(e + 255) / 256, blk, 0, stream>>>(src, dst, cursor, adj, e);

    // layer 1
    gemm1_kernel<<<(n + 7) / 8, blk, 0, stream>>>(x, W1, dinv, g1, n);
    agg1_kernel<<<(n * 32 + 255) / 256, blk, 0, stream>>>(offs, counts, adj, dinv, g1, b1, agg1, n);

    // layer 2
    gemm2_kernel<<<(n + 15) / 16, blk, 0, stream>>>(agg1, W2, dinv, g2, n);
    agg2_kernel<<<(n * 16 + 255) / 256, blk, 0, stream>>>(offs, counts, adj, dinv, g2, b2, z, n);

    // decode
    decode_kernel<<<(e + 255) / 256, blk, 0, stream>>>(src, dst, z, out, e);
}